// Round 1
// baseline (727.445 us; speedup 1.0000x reference)
//
#include <hip/hip_runtime.h>
#include <hip/hip_bf16.h>
#include <math.h>

#define LSEQ 128
#define BB 8
#define M_TOK (BB*LSEQ)   // 1024

// ---------------- weight transpose: w[oc][ci][k] -> wT[(ci*K+k)*OC+oc] ----------------
__global__ void transpose_w_kernel(const float* __restrict__ w, float* __restrict__ wT,
                                   int OC, int CIN, int K) {
    int idx = blockIdx.x * 256 + threadIdx.x;
    int total = OC * CIN * K;
    if (idx >= total) return;
    int k = idx % K;
    int r = idx / K;
    int ci = r % CIN;
    int oc = r / CIN;
    wT[(ci * K + k) * OC + oc] = w[idx];
}

// ---------------- embedding gather: emb[b][l][c], c<300 gen, else domain ----------------
__global__ __launch_bounds__(128) void embed_kernel(const int* __restrict__ x,
        const float* __restrict__ gen, const float* __restrict__ dom,
        float* __restrict__ emb) {
    int m = blockIdx.x;          // b*L + l
    int t = x[m];
    float* dst = emb + m * 400;
    for (int c = threadIdx.x; c < 400; c += 128) {
        dst[c] = (c < 300) ? gen[t * 300 + c] : dom[t * 100 + (c - 300)];
    }
}

// ---------------- conv1: 400ch -> 128 (k=5,p=2) concat 128 (k=3,p=1), relu ----------------
// in: emb[b][l][400]; out: y[b][l][256]
__global__ __launch_bounds__(256) void conv1_kernel(const float* __restrict__ emb,
        const float* __restrict__ w1T, const float* __restrict__ b1,
        const float* __restrict__ w2T, const float* __restrict__ b2,
        float* __restrict__ out) {
    __shared__ float lds[8 * 400];
    int b = blockIdx.x;
    int l0 = blockIdx.y * 4;
    int tid = threadIdx.x;
    #pragma unroll
    for (int j = 0; j < 8; ++j) {
        int l = l0 - 2 + j;
        const float* src = emb + (b * LSEQ + l) * 400;
        bool ok = (l >= 0 && l < LSEQ);
        for (int c = tid; c < 400; c += 256) lds[j * 400 + c] = ok ? src[c] : 0.f;
    }
    __syncthreads();
    int oc = tid;
    float a0, a1, a2, a3;
    if (oc < 128) {
        a0 = a1 = a2 = a3 = b1[oc];
        #pragma unroll 2
        for (int ci = 0; ci < 400; ++ci) {
            float v[8];
            #pragma unroll
            for (int j = 0; j < 8; ++j) v[j] = lds[j * 400 + ci];
            #pragma unroll
            for (int k = 0; k < 5; ++k) {
                float w = w1T[(ci * 5 + k) * 128 + oc];
                a0 += w * v[k]; a1 += w * v[k + 1]; a2 += w * v[k + 2]; a3 += w * v[k + 3];
            }
        }
    } else {
        int o2 = oc - 128;
        a0 = a1 = a2 = a3 = b2[o2];
        #pragma unroll 2
        for (int ci = 0; ci < 400; ++ci) {
            float v[8];
            #pragma unroll
            for (int j = 0; j < 8; ++j) v[j] = lds[j * 400 + ci];
            #pragma unroll
            for (int k = 0; k < 3; ++k) {
                float w = w2T[(ci * 3 + k) * 128 + o2];
                a0 += w * v[k + 1]; a1 += w * v[k + 2]; a2 += w * v[k + 3]; a3 += w * v[k + 4];
            }
        }
    }
    float acc[4] = {a0, a1, a2, a3};
    #pragma unroll
    for (int j = 0; j < 4; ++j) {
        out[(b * LSEQ + l0 + j) * 256 + oc] = fmaxf(acc[j], 0.f);
    }
}

// ---------------- conv 256->256, k=5, p=2, relu; layouts [b][l][256] ----------------
__global__ __launch_bounds__(256) void conv256_kernel(const float* __restrict__ in,
        const float* __restrict__ wT, const float* __restrict__ bias,
        float* __restrict__ out) {
    __shared__ float lds[8 * 256];
    int b = blockIdx.x;
    int l0 = blockIdx.y * 4;
    int tid = threadIdx.x;
    #pragma unroll
    for (int j = 0; j < 8; ++j) {
        int l = l0 - 2 + j;
        bool ok = (l >= 0 && l < LSEQ);
        lds[j * 256 + tid] = ok ? in[(b * LSEQ + l) * 256 + tid] : 0.f;
    }
    __syncthreads();
    int oc = tid;
    float a0, a1, a2, a3;
    a0 = a1 = a2 = a3 = bias[oc];
    #pragma unroll 2
    for (int ci = 0; ci < 256; ++ci) {
        float v[8];
        #pragma unroll
        for (int j = 0; j < 8; ++j) v[j] = lds[j * 256 + ci];
        #pragma unroll
        for (int k = 0; k < 5; ++k) {
            float w = wT[(ci * 5 + k) * 256 + oc];
            a0 += w * v[k]; a1 += w * v[k + 1]; a2 += w * v[k + 2]; a3 += w * v[k + 3];
        }
    }
    float acc[4] = {a0, a1, a2, a3};
    #pragma unroll
    for (int j = 0; j < 4; ++j) {
        out[(b * LSEQ + l0 + j) * 256 + oc] = fmaxf(acc[j], 0.f);
    }
}

// ---------------- q/v projection: q = xc@wq+bq, v = xc@wv+bv (ATT_DIM=50) ----------------
__global__ __launch_bounds__(64) void qv_kernel(const float* __restrict__ xc,
        const float* __restrict__ wq, const float* __restrict__ bq,
        const float* __restrict__ wv, const float* __restrict__ bv,
        float* __restrict__ q, float* __restrict__ v) {
    int m = blockIdx.x;
    int d = threadIdx.x;
    if (d >= 50) return;
    float aq = bq[d], av = bv[d];
    for (int c = 0; c < 256; ++c) {
        float xv = xc[m * 256 + c];
        aq += xv * wq[c * 50 + d];
        av += xv * wv[c * 50 + d];
    }
    q[m * 50 + d] = aq;
    v[m * 50 + d] = av;
}

// ---------------- attention: scores = tanh(q_i+v_j)@vv, softmax_j, xc2 = xc + attn@xc ----------------
__global__ __launch_bounds__(128) void attn_kernel(const float* __restrict__ xc,
        const float* __restrict__ q, const float* __restrict__ v,
        const float* __restrict__ vv, const float* __restrict__ xmask,
        float* __restrict__ xc2) {
    __shared__ float qrow[50], vvs[50], red[128], aarr[128];
    int bi = blockIdx.x;          // b*L + i
    int b = bi >> 7;
    int tid = threadIdx.x;        // j
    if (tid < 50) { qrow[tid] = q[bi * 50 + tid]; vvs[tid] = vv[tid]; }
    __syncthreads();
    const float* vj = v + (b * LSEQ + tid) * 50;
    float s = 0.f;
    for (int d = 0; d < 50; ++d) s += tanhf(qrow[d] + vj[d]) * vvs[d];
    if (xmask[b * LSEQ + tid] == 0.f) s = -1e9f;
    // max over 128
    red[tid] = s; __syncthreads();
    for (int off = 64; off >= 1; off >>= 1) {
        if (tid < off) red[tid] = fmaxf(red[tid], red[tid + off]);
        __syncthreads();
    }
    float mx = red[0];
    __syncthreads();
    float e = expf(s - mx);
    red[tid] = e; __syncthreads();
    for (int off = 64; off >= 1; off >>= 1) {
        if (tid < off) red[tid] += red[tid + off];
        __syncthreads();
    }
    float denom = red[0];
    __syncthreads();
    aarr[tid] = e / denom;
    __syncthreads();
    float maskI = xmask[bi];
    for (int c = tid; c < 256; c += 128) {
        float acc = 0.f;
        for (int j = 0; j < LSEQ; ++j) acc += aarr[j] * xc[(b * LSEQ + j) * 256 + c];
        xc2[bi * 256 + c] = xc[bi * 256 + c] + acc * maskI;
    }
}

// ---------------- 6-dim projection: out[m][c] = A[m]@W[:,c] (+bias) ----------------
__global__ __launch_bounds__(64) void proj6_kernel(const float* __restrict__ A, int K,
        const float* __restrict__ W, const float* __restrict__ bias,
        float* __restrict__ out) {
    int m = blockIdx.x;
    int tid = threadIdx.x;
    float p[6] = {0, 0, 0, 0, 0, 0};
    for (int k = tid; k < K; k += 64) {
        float a = A[m * K + k];
        #pragma unroll
        for (int c = 0; c < 6; ++c) p[c] += a * W[k * 6 + c];
    }
    #pragma unroll
    for (int c = 0; c < 6; ++c) {
        for (int off = 32; off >= 1; off >>= 1) p[c] += __shfl_down(p[c], off, 64);
    }
    if (tid == 0) {
        #pragma unroll
        for (int c = 0; c < 6; ++c) out[m * 6 + c] = p[c] + (bias ? bias[c] : 0.f);
    }
}

// ---------------- lm scan: lm[b,p,c] from separable probs = f_i + g_j, lg = probs*triu ----------------
// M1[p] = (prefixmax_{i<=p} f) + g[p], max(·,0) if p<L-1 (zeros present in column)
// M2[p] = f[p] + (suffixmax_{j>=p} g), max(·,0) if p>0   (zeros present in row)
__global__ void lm_scan_kernel(const float* __restrict__ f, const float* __restrict__ g,
                               float* __restrict__ lm) {
    int tid = threadIdx.x;
    if (tid >= 48) return;
    int b = tid / 6, c = tid % 6;
    float runf = -INFINITY;
    for (int p = 0; p < LSEQ; ++p) {
        int idx = (b * LSEQ + p) * 6 + c;
        runf = fmaxf(runf, f[idx]);
        float M1 = runf + g[idx];
        if (p < LSEQ - 1) M1 = fmaxf(M1, 0.f);
        lm[idx] = M1;
    }
    float rung = -INFINITY;
    for (int p = LSEQ - 1; p >= 0; --p) {
        int idx = (b * LSEQ + p) * 6 + c;
        rung = fmaxf(rung, g[idx]);
        float M2 = f[idx] + rung;
        if (p > 0) M2 = fmaxf(M2, 0.f);
        lm[idx] = fmaxf(lm[idx], M2);
    }
}

// ---------------- hop GEMM: out[m][n] = A[m]@W[:,n] + lm[m]@wf[lmoff:lmoff+6] + fg[m]@wf[524:530] (+bf) ----------------
__global__ __launch_bounds__(256) void hop_gemm_kernel(const float* __restrict__ A, int K,
        const float* __restrict__ W,      // K x 512 (already offset into wf)
        const float* __restrict__ wf,     // base (530 x 512)
        int lmoff,
        const float* __restrict__ lm, const float* __restrict__ fg,
        const float* __restrict__ bias,   // 512 or null
        float* __restrict__ out) {
    int m0 = blockIdx.x * 8;
    int n = blockIdx.y * 256 + threadIdx.x;
    float binit = bias ? bias[n] : 0.f;
    float acc[8];
    #pragma unroll
    for (int mm = 0; mm < 8; ++mm) acc[mm] = binit;
    #pragma unroll 4
    for (int k = 0; k < K; ++k) {
        float w = W[k * 512 + n];
        #pragma unroll
        for (int mm = 0; mm < 8; ++mm) acc[mm] += A[(m0 + mm) * K + k] * w;
    }
    #pragma unroll
    for (int c = 0; c < 6; ++c) {
        float wB = wf[(lmoff + c) * 512 + n];
        float wD = wf[(524 + c) * 512 + n];
        #pragma unroll
        for (int mm = 0; mm < 8; ++mm)
            acc[mm] += lm[(m0 + mm) * 6 + c] * wB + fg[(m0 + mm) * 6 + c] * wD;
    }
    #pragma unroll
    for (int mm = 0; mm < 8; ++mm) out[(m0 + mm) * 512 + n] = acc[mm];
}

// ---------------- final separable write: out[b,i,j,c] = f2[b,i,c] + g2[b,j,c] ----------------
__global__ __launch_bounds__(256) void writeout_kernel(const float* __restrict__ f2,
        const float* __restrict__ g2, float* __restrict__ out) {
    int idx = blockIdx.x * 256 + threadIdx.x;   // < 8*128*128*6
    int c = idx % 6;
    int r = idx / 6;          // (b*L+i)*L + j
    int j = r & 127;
    int bi = r >> 7;          // b*L + i
    int b = bi >> 7;
    out[idx] = f2[bi * 6 + c] + g2[(b * LSEQ + j) * 6 + c];
}

extern "C" void kernel_launch(void* const* d_in, const int* in_sizes, int n_in,
                              void* d_out, int out_size, void* d_ws, size_t ws_size,
                              hipStream_t stream) {
    const int*   x     = (const int*)d_in[0];
    // d_in[1] = x_len (always 128), ignored
    const float* xmask = (const float*)d_in[2];
    const float* gen   = (const float*)d_in[3];
    const float* dom   = (const float*)d_in[4];
    const float* w1    = (const float*)d_in[5];
    const float* b1    = (const float*)d_in[6];
    const float* w2    = (const float*)d_in[7];
    const float* b2    = (const float*)d_in[8];
    const float* w3    = (const float*)d_in[9];
    const float* b3    = (const float*)d_in[10];
    const float* w4    = (const float*)d_in[11];
    const float* b4    = (const float*)d_in[12];
    const float* w5    = (const float*)d_in[13];
    const float* b5    = (const float*)d_in[14];
    const float* wq    = (const float*)d_in[15];
    const float* bq    = (const float*)d_in[16];
    const float* wv    = (const float*)d_in[17];
    const float* bv    = (const float*)d_in[18];
    const float* vv    = (const float*)d_in[19];
    const float* wf    = (const float*)d_in[20];
    const float* bf    = (const float*)d_in[21];
    const float* wc    = (const float*)d_in[22];
    const float* bc    = (const float*)d_in[23];

    float* ws = (float*)d_ws;
    float* emb  = ws;                 // 409600
    float* bufA = emb  + 409600;      // 262144
    float* bufB = bufA + 262144;      // 262144
    float* xc2  = bufB + 262144;      // 262144
    float* qb   = xc2  + 262144;      // 51200
    float* vb   = qb   + 51200;       // 51200
    float* wscr = vb   + 51200;       // 409600 (reused per conv layer)
    float* F1   = wscr + 409600;      // 524288
    float* G1   = F1   + 524288;      // 524288
    float* F2   = G1   + 524288;      // 524288
    float* G2   = F2   + 524288;      // 524288
    float* f0   = G2   + 524288;      // 6144 each below
    float* g0   = f0 + 6144;
    float* f1   = g0 + 6144;
    float* g1   = f1 + 6144;
    float* f2   = g1 + 6144;
    float* g2   = f2 + 6144;
    float* lm0  = g2 + 6144;
    float* lm1  = lm0 + 6144;

    float* w1T = wscr;                // 128*400*5 = 256000
    float* w2T = wscr + 256000;       // 128*400*3 = 153600

    // embedding
    embed_kernel<<<M_TOK, 128, 0, stream>>>(x, gen, dom, emb);

    // conv1 (+concat conv2) + relu
    transpose_w_kernel<<<(128*400*5 + 255)/256, 256, 0, stream>>>(w1, w1T, 128, 400, 5);
    transpose_w_kernel<<<(128*400*3 + 255)/256, 256, 0, stream>>>(w2, w2T, 128, 400, 3);
    conv1_kernel<<<dim3(BB, 32), 256, 0, stream>>>(emb, w1T, b1, w2T, b2, bufA);

    // conv3, conv4, conv5 (reuse wscr for each transposed weight)
    transpose_w_kernel<<<(256*256*5 + 255)/256, 256, 0, stream>>>(w3, wscr, 256, 256, 5);
    conv256_kernel<<<dim3(BB, 32), 256, 0, stream>>>(bufA, wscr, b3, bufB);
    transpose_w_kernel<<<(256*256*5 + 255)/256, 256, 0, stream>>>(w4, wscr, 256, 256, 5);
    conv256_kernel<<<dim3(BB, 32), 256, 0, stream>>>(bufB, wscr, b4, bufA);
    transpose_w_kernel<<<(256*256*5 + 255)/256, 256, 0, stream>>>(w5, wscr, 256, 256, 5);
    conv256_kernel<<<dim3(BB, 32), 256, 0, stream>>>(bufA, wscr, b5, bufB);
    // xc = bufB  (B,L,256)

    // attention
    qv_kernel<<<M_TOK, 64, 0, stream>>>(bufB, wq, bq, wv, bv, qb, vb);
    attn_kernel<<<M_TOK, 128, 0, stream>>>(bufB, qb, vb, vv, xmask, xc2);

    // hop 0: logits_0 separable: f0 = xc2@wc[0:256]+bc, g0 = xc2@wc[256:512]
    proj6_kernel<<<M_TOK, 64, 0, stream>>>(xc2, 256, wc, bc, f0);
    proj6_kernel<<<M_TOK, 64, 0, stream>>>(xc2, 256, wc + 256*6, nullptr, g0);
    lm_scan_kernel<<<1, 64, 0, stream>>>(f0, g0, lm0);

    // hop 1: F1 = xc2@wf[0:256] + lm0@wf[512:518] + f0@wf[524:530] + bf
    //        G1 = xc2@wf[256:512] + lm0@wf[518:524] + g0@wf[524:530]
    hop_gemm_kernel<<<dim3(128, 2), 256, 0, stream>>>(xc2, 256, wf,           wf, 512, lm0, f0, bf,      F1);
    hop_gemm_kernel<<<dim3(128, 2), 256, 0, stream>>>(xc2, 256, wf + 256*512, wf, 518, lm0, g0, nullptr, G1);
    proj6_kernel<<<M_TOK, 64, 0, stream>>>(F1, 512, wc, bc, f1);
    proj6_kernel<<<M_TOK, 64, 0, stream>>>(G1, 512, wc, nullptr, g1);
    lm_scan_kernel<<<1, 64, 0, stream>>>(f1, g1, lm1);

    // hop 2: F2 = F1@wf[0:512] + lm1@wf[512:518] + f1@wf[524:530] + bf ; G2 analogous
    hop_gemm_kernel<<<dim3(128, 2), 256, 0, stream>>>(F1, 512, wf, wf, 512, lm1, f1, bf,      F2);
    hop_gemm_kernel<<<dim3(128, 2), 256, 0, stream>>>(G1, 512, wf, wf, 518, lm1, g1, nullptr, G2);
    proj6_kernel<<<M_TOK, 64, 0, stream>>>(F2, 512, wc, bc, f2);
    proj6_kernel<<<M_TOK, 64, 0, stream>>>(G2, 512, wc, nullptr, g2);

    // out[b,i,j,c] = f2[b,i,c] + g2[b,j,c]
    writeout_kernel<<<(BB*LSEQ*LSEQ*6)/256, 256, 0, stream>>>(f2, g2, (float*)d_out);
}

// Round 2
// 364.486 us; speedup vs baseline: 1.9958x; 1.9958x over previous
//
#include <hip/hip_runtime.h>
#include <hip/hip_bf16.h>
#include <math.h>

#define LSEQ 128
#define BB 8
#define M_TOK (BB*LSEQ)   // 1024

// ---------------- weight transpose: w[oc][ci][k] -> wT[(ci*K+k)*OC+oc] ----------------
__global__ void transpose_w_kernel(const float* __restrict__ w, float* __restrict__ wT,
                                   int OC, int CIN, int K) {
    int idx = blockIdx.x * 256 + threadIdx.x;
    int total = OC * CIN * K;
    if (idx >= total) return;
    int k = idx % K;
    int r = idx / K;
    int ci = r % CIN;
    int oc = r / CIN;
    wT[(ci * K + k) * OC + oc] = w[idx];
}

// ---------------- embedding gather ----------------
__global__ __launch_bounds__(128) void embed_kernel(const int* __restrict__ x,
        const float* __restrict__ gen, const float* __restrict__ dom,
        float* __restrict__ emb) {
    int m = blockIdx.x;          // b*L + l
    int t = x[m];
    float* dst = emb + m * 400;
    for (int c = threadIdx.x; c < 400; c += 128) {
        dst[c] = (c < 300) ? gen[t * 300 + c] : dom[t * 100 + (c - 300)];
    }
}

// ---------------- conv1 v2: 400ch -> 128(k=5,p=2) ++ 128(k=3,p=1), relu ----------------
// grid (64 pos-tiles, 8 oc-tiles), block 256 = 32 oc-lanes x 8 ci-slices
// LDS xs[ci][20] stride-20 (float4-aligned rows); reduce over slices in LDS.
__global__ __launch_bounds__(256) void conv1_v2(const float* __restrict__ emb,
        const float* __restrict__ w1T, const float* __restrict__ b1,
        const float* __restrict__ w2T, const float* __restrict__ b2,
        float* __restrict__ out) {
    __shared__ float xs[400 * 20];   // 32 KB
    int pt = blockIdx.x;             // pos tile
    int b = pt >> 3;
    int l0 = (pt & 7) << 4;
    int ot = blockIdx.y;             // oc tile (0..3: conv k=5, 4..7: conv k=3)
    int tid = threadIdx.x;
    // stage X: positions l0-2 .. l0+17, all 400 ci
    for (int idx = tid; idx < 400 * 20; idx += 256) {
        int p = idx / 400;
        int ci = idx - p * 400;
        int l = l0 - 2 + p;
        float v = 0.f;
        if (l >= 0 && l < LSEQ) v = emb[(b * LSEQ + l) * 400 + ci];
        xs[ci * 20 + p] = v;
    }
    __syncthreads();
    int o = tid & 31;
    int s = tid >> 5;                // ci-slice: [s*50, s*50+50)
    float acc[16];
    #pragma unroll
    for (int p = 0; p < 16; ++p) acc[p] = 0.f;
    if (ot < 4) {
        int oc0 = ot * 32;
        const float* wp = w1T + (s * 50 * 5) * 128 + oc0 + o;
        int cbase = s * 50;
        for (int i = 0; i < 50; ++i) {
            const float4* x4 = (const float4*)(xs + (cbase + i) * 20);
            float4 A0 = x4[0], A1 = x4[1], A2 = x4[2], A3 = x4[3], A4 = x4[4];
            float xv[20] = {A0.x,A0.y,A0.z,A0.w, A1.x,A1.y,A1.z,A1.w,
                            A2.x,A2.y,A2.z,A2.w, A3.x,A3.y,A3.z,A3.w,
                            A4.x,A4.y,A4.z,A4.w};
            #pragma unroll
            for (int k = 0; k < 5; ++k) {
                float w = wp[k * 128];
                #pragma unroll
                for (int p = 0; p < 16; ++p) acc[p] += w * xv[p + k];
            }
            wp += 640;
        }
    } else {
        int oc0 = (ot - 4) * 32;
        const float* wp = w2T + (s * 50 * 3) * 128 + oc0 + o;
        int cbase = s * 50;
        for (int i = 0; i < 50; ++i) {
            const float4* x4 = (const float4*)(xs + (cbase + i) * 20);
            float4 A0 = x4[0], A1 = x4[1], A2 = x4[2], A3 = x4[3], A4 = x4[4];
            float xv[20] = {A0.x,A0.y,A0.z,A0.w, A1.x,A1.y,A1.z,A1.w,
                            A2.x,A2.y,A2.z,A2.w, A3.x,A3.y,A3.z,A3.w,
                            A4.x,A4.y,A4.z,A4.w};
            #pragma unroll
            for (int k = 0; k < 3; ++k) {
                float w = wp[k * 128];
                #pragma unroll
                for (int p = 0; p < 16; ++p) acc[p] += w * xv[p + k + 1];
            }
            wp += 384;
        }
    }
    __syncthreads();
    float* rs = xs;                  // 8 x 16 x 32 = 4096 floats
    #pragma unroll
    for (int p = 0; p < 16; ++p) rs[s * 512 + p * 32 + o] = acc[p];
    __syncthreads();
    float bias = (ot < 4) ? b1[ot * 32 + (tid & 31)] : b2[(ot - 4) * 32 + (tid & 31)];
    // note: each thread below handles 2 outputs with its own o from idx
    #pragma unroll
    for (int r = 0; r < 2; ++r) {
        int idx = r * 256 + tid;
        int p = idx >> 5, oo = idx & 31;
        float sum = 0.f;
        #pragma unroll
        for (int ss = 0; ss < 8; ++ss) sum += rs[ss * 512 + p * 32 + oo];
        float bs = (ot < 4) ? b1[ot * 32 + oo] : b2[(ot - 4) * 32 + oo];
        out[(b * LSEQ + l0 + p) * 256 + ot * 32 + oo] = fmaxf(sum + bs, 0.f);
    }
    (void)bias;
}

// ---------------- conv256 v2: 256->256, k=5, p=2, relu ----------------
__global__ __launch_bounds__(256) void conv256_v2(const float* __restrict__ in,
        const float* __restrict__ wT, const float* __restrict__ bias,
        float* __restrict__ out) {
    __shared__ float xs[256 * 20];   // 20.5 KB
    int pt = blockIdx.x;
    int b = pt >> 3;
    int l0 = (pt & 7) << 4;
    int ot = blockIdx.y;             // oc tile, 8 of 32
    int tid = threadIdx.x;
    for (int idx = tid; idx < 256 * 20; idx += 256) {
        int p = idx >> 8;
        int ci = idx & 255;
        int l = l0 - 2 + p;
        float v = 0.f;
        if (l >= 0 && l < LSEQ) v = in[(b * LSEQ + l) * 256 + ci];
        xs[ci * 20 + p] = v;
    }
    __syncthreads();
    int o = tid & 31;
    int s = tid >> 5;                // ci-slice [s*32, s*32+32)
    int oc0 = ot * 32;
    float acc[16];
    #pragma unroll
    for (int p = 0; p < 16; ++p) acc[p] = 0.f;
    const float* wp = wT + (s * 32 * 5) * 256 + oc0 + o;
    for (int i = 0; i < 32; ++i) {
        const float4* x4 = (const float4*)(xs + (s * 32 + i) * 20);
        float4 A0 = x4[0], A1 = x4[1], A2 = x4[2], A3 = x4[3], A4 = x4[4];
        float xv[20] = {A0.x,A0.y,A0.z,A0.w, A1.x,A1.y,A1.z,A1.w,
                        A2.x,A2.y,A2.z,A2.w, A3.x,A3.y,A3.z,A3.w,
                        A4.x,A4.y,A4.z,A4.w};
        #pragma unroll
        for (int k = 0; k < 5; ++k) {
            float w = wp[k * 256];
            #pragma unroll
            for (int p = 0; p < 16; ++p) acc[p] += w * xv[p + k];
        }
        wp += 1280;
    }
    __syncthreads();
    float* rs = xs;
    #pragma unroll
    for (int p = 0; p < 16; ++p) rs[s * 512 + p * 32 + o] = acc[p];
    __syncthreads();
    #pragma unroll
    for (int r = 0; r < 2; ++r) {
        int idx = r * 256 + tid;
        int p = idx >> 5, oo = idx & 31;
        float sum = 0.f;
        #pragma unroll
        for (int ss = 0; ss < 8; ++ss) sum += rs[ss * 512 + p * 32 + oo];
        out[(b * LSEQ + l0 + p) * 256 + oc0 + oo] = fmaxf(sum + bias[oc0 + oo], 0.f);
    }
}

// ---------------- q/v projection ----------------
__global__ __launch_bounds__(64) void qv_kernel(const float* __restrict__ xc,
        const float* __restrict__ wq, const float* __restrict__ bq,
        const float* __restrict__ wv, const float* __restrict__ bv,
        float* __restrict__ q, float* __restrict__ v) {
    int m = blockIdx.x;
    int d = threadIdx.x;
    if (d >= 50) return;
    float aq = bq[d], av = bv[d];
    for (int c = 0; c < 256; ++c) {
        float xv = xc[m * 256 + c];
        aq += xv * wq[c * 50 + d];
        av += xv * wv[c * 50 + d];
    }
    q[m * 50 + d] = aq;
    v[m * 50 + d] = av;
}

// ---------------- attention ----------------
__global__ __launch_bounds__(128) void attn_kernel(const float* __restrict__ xc,
        const float* __restrict__ q, const float* __restrict__ v,
        const float* __restrict__ vv, const float* __restrict__ xmask,
        float* __restrict__ xc2) {
    __shared__ float qrow[50], vvs[50], red[128], aarr[128];
    int bi = blockIdx.x;          // b*L + i
    int b = bi >> 7;
    int tid = threadIdx.x;        // j
    if (tid < 50) { qrow[tid] = q[bi * 50 + tid]; vvs[tid] = vv[tid]; }
    __syncthreads();
    const float* vj = v + (b * LSEQ + tid) * 50;
    float s = 0.f;
    for (int d = 0; d < 50; ++d) s += tanhf(qrow[d] + vj[d]) * vvs[d];
    if (xmask[b * LSEQ + tid] == 0.f) s = -1e9f;
    red[tid] = s; __syncthreads();
    for (int off = 64; off >= 1; off >>= 1) {
        if (tid < off) red[tid] = fmaxf(red[tid], red[tid + off]);
        __syncthreads();
    }
    float mx = red[0];
    __syncthreads();
    float e = expf(s - mx);
    red[tid] = e; __syncthreads();
    for (int off = 64; off >= 1; off >>= 1) {
        if (tid < off) red[tid] += red[tid + off];
        __syncthreads();
    }
    float denom = red[0];
    __syncthreads();
    aarr[tid] = e / denom;
    __syncthreads();
    float maskI = xmask[bi];
    for (int c = tid; c < 256; c += 128) {
        float acc = 0.f;
        for (int j = 0; j < LSEQ; ++j) acc += aarr[j] * xc[(b * LSEQ + j) * 256 + c];
        xc2[bi * 256 + c] = xc[bi * 256 + c] + acc * maskI;
    }
}

// ---------------- dual 6-dim projection: f and g in one launch ----------------
__global__ __launch_bounds__(64) void proj6_dual_kernel(
        const float* __restrict__ A0, const float* __restrict__ W0,
        const float* __restrict__ bias0, float* __restrict__ out0,
        const float* __restrict__ A1, const float* __restrict__ W1,
        const float* __restrict__ bias1, float* __restrict__ out1, int K) {
    int m = blockIdx.x;
    int y = blockIdx.y;
    const float* A = y ? A1 : A0;
    const float* W = y ? W1 : W0;
    const float* bias = y ? bias1 : bias0;
    float* out = y ? out1 : out0;
    int tid = threadIdx.x;
    float p[6] = {0, 0, 0, 0, 0, 0};
    for (int k = tid; k < K; k += 64) {
        float a = A[m * K + k];
        #pragma unroll
        for (int c = 0; c < 6; ++c) p[c] += a * W[k * 6 + c];
    }
    #pragma unroll
    for (int c = 0; c < 6; ++c) {
        for (int off = 32; off >= 1; off >>= 1) p[c] += __shfl_down(p[c], off, 64);
    }
    if (tid == 0) {
        #pragma unroll
        for (int c = 0; c < 6; ++c) out[m * 6 + c] = p[c] + (bias ? bias[c] : 0.f);
    }
}

// ---------------- lm scan v2: parallel prefix/suffix max, 48 blocks x 128 ----------------
// M1[p] = (prefixmax_{i<=p} f) + g[p], relu'd if p<L-1; M2[p] = f[p] + suffixmax g, relu'd if p>0
__global__ __launch_bounds__(128) void lm_scan_v2(const float* __restrict__ f,
        const float* __restrict__ g, float* __restrict__ lm) {
    __shared__ float sf[128], sg[128];
    int bc = blockIdx.x;          // b*6 + c
    int b = bc / 6, c = bc - b * 6;
    int p = threadIdx.x;
    int idx = (b * LSEQ + p) * 6 + c;
    float fv = f[idx], gv = g[idx];
    sf[p] = fv; sg[p] = gv;
    __syncthreads();
    float pf = fv, sgx = gv;
    #pragma unroll
    for (int off = 1; off < 128; off <<= 1) {
        float a = (p >= off) ? sf[p - off] : -INFINITY;
        float d = (p + off < 128) ? sg[p + off] : -INFINITY;
        __syncthreads();
        pf = fmaxf(pf, a); sgx = fmaxf(sgx, d);
        sf[p] = pf; sg[p] = sgx;
        __syncthreads();
    }
    float M1 = pf + gv;
    if (p < LSEQ - 1) M1 = fmaxf(M1, 0.f);
    float M2 = fv + sgx;
    if (p > 0) M2 = fmaxf(M2, 0.f);
    lm[idx] = fmaxf(M1, M2);
}

// ---------------- hop GEMM v2: out[m][n] = A[m]@W[:,n] + lm@wf[lmoff..] + fg@wf[524..] (+bias) ----------------
// grid (64 m-tiles, 8 n-tiles), block 256 = 64 n-lanes x 4 k-slices; LDS A-tile stride-20
__global__ __launch_bounds__(256) void hop_gemm_v2(const float* __restrict__ A, int K, int kshift,
        const float* __restrict__ W,      // K x 512 (offset into wf rows)
        const float* __restrict__ wf,     // base (530 x 512)
        int lmoff,
        const float* __restrict__ lm, const float* __restrict__ fg,
        const float* __restrict__ bias,   // 512 or null
        float* __restrict__ out) {
    __shared__ float xs[512 * 20];   // 40 KB (hop1 uses first 256*20)
    int m0 = blockIdx.x * 16;
    int n0 = blockIdx.y * 64;
    int tid = threadIdx.x;
    int tot = K << 4;
    for (int idx = tid; idx < tot; idx += 256) {
        int m = idx >> kshift;
        int k = idx & (K - 1);
        xs[k * 20 + m] = A[(m0 + m) * K + k];
    }
    __syncthreads();
    int o = tid & 63;
    int s = tid >> 6;
    int kc = K >> 2;
    int kb = s * kc;
    float acc[16];
    #pragma unroll
    for (int p = 0; p < 16; ++p) acc[p] = 0.f;
    const float* Wp = W + (size_t)kb * 512 + n0 + o;
    for (int kk = 0; kk < kc; ++kk) {
        const float4* x4 = (const float4*)(xs + (kb + kk) * 20);
        float4 A0 = x4[0], A1 = x4[1], A2 = x4[2], A3 = x4[3];
        float w = Wp[kk * 512];
        acc[0]  += A0.x * w; acc[1]  += A0.y * w; acc[2]  += A0.z * w; acc[3]  += A0.w * w;
        acc[4]  += A1.x * w; acc[5]  += A1.y * w; acc[6]  += A1.z * w; acc[7]  += A1.w * w;
        acc[8]  += A2.x * w; acc[9]  += A2.y * w; acc[10] += A2.z * w; acc[11] += A2.w * w;
        acc[12] += A3.x * w; acc[13] += A3.y * w; acc[14] += A3.z * w; acc[15] += A3.w * w;
    }
    __syncthreads();
    float* rs = xs;                  // 4 x 16 x 64 = 4096 floats
    #pragma unroll
    for (int p = 0; p < 16; ++p) rs[s * 1024 + p * 64 + o] = acc[p];
    __syncthreads();
    #pragma unroll
    for (int r = 0; r < 4; ++r) {
        int idx = r * 256 + tid;
        int m = idx >> 6, oo = idx & 63;
        int n = n0 + oo;
        float sum = 0.f;
        #pragma unroll
        for (int ss = 0; ss < 4; ++ss) sum += rs[ss * 1024 + m * 64 + oo];
        if (bias) sum += bias[n];
        #pragma unroll
        for (int c = 0; c < 6; ++c) {
            sum += lm[(m0 + m) * 6 + c] * wf[(lmoff + c) * 512 + n]
                 + fg[(m0 + m) * 6 + c] * wf[(524 + c) * 512 + n];
        }
        out[(m0 + m) * 512 + n] = sum;
    }
}

// ---------------- final separable write ----------------
__global__ __launch_bounds__(256) void writeout_kernel(const float* __restrict__ f2,
        const float* __restrict__ g2, float* __restrict__ out) {
    int idx = blockIdx.x * 256 + threadIdx.x;   // < 8*128*128*6
    int c = idx % 6;
    int r = idx / 6;          // (b*L+i)*L + j
    int j = r & 127;
    int bi = r >> 7;          // b*L + i
    int b = bi >> 7;
    out[idx] = f2[bi * 6 + c] + g2[(b * LSEQ + j) * 6 + c];
}

extern "C" void kernel_launch(void* const* d_in, const int* in_sizes, int n_in,
                              void* d_out, int out_size, void* d_ws, size_t ws_size,
                              hipStream_t stream) {
    const int*   x     = (const int*)d_in[0];
    const float* xmask = (const float*)d_in[2];
    const float* gen   = (const float*)d_in[3];
    const float* dom   = (const float*)d_in[4];
    const float* w1    = (const float*)d_in[5];
    const float* b1    = (const float*)d_in[6];
    const float* w2    = (const float*)d_in[7];
    const float* b2    = (const float*)d_in[8];
    const float* w3    = (const float*)d_in[9];
    const float* b3    = (const float*)d_in[10];
    const float* w4    = (const float*)d_in[11];
    const float* b4    = (const float*)d_in[12];
    const float* w5    = (const float*)d_in[13];
    const float* b5    = (const float*)d_in[14];
    const float* wq    = (const float*)d_in[15];
    const float* bq    = (const float*)d_in[16];
    const float* wv    = (const float*)d_in[17];
    const float* bv    = (const float*)d_in[18];
    const float* vv    = (const float*)d_in[19];
    const float* wf    = (const float*)d_in[20];
    const float* bf    = (const float*)d_in[21];
    const float* wc    = (const float*)d_in[22];
    const float* bc    = (const float*)d_in[23];

    float* ws = (float*)d_ws;
    float* emb  = ws;                 // 409600
    float* bufA = emb  + 409600;      // 262144
    float* bufB = bufA + 262144;      // 262144
    float* xc2  = bufB + 262144;      // 262144
    float* qb   = xc2  + 262144;      // 51200
    float* vb   = qb   + 51200;       // 51200
    float* wscr = vb   + 51200;       // 409600 (reused per conv layer)
    float* F1   = wscr + 409600;      // 524288
    float* G1   = F1   + 524288;      // 524288
    float* F2   = G1   + 524288;      // 524288
    float* G2   = F2   + 524288;      // 524288
    float* f0   = G2   + 524288;
    float* g0   = f0 + 6144;
    float* f1   = g0 + 6144;
    float* g1   = f1 + 6144;
    float* f2   = g1 + 6144;
    float* g2   = f2 + 6144;
    float* lm0  = g2 + 6144;
    float* lm1  = lm0 + 6144;

    float* w1T = wscr;                // 128*400*5 = 256000
    float* w2T = wscr + 256000;       // 128*400*3 = 153600

    // embedding
    embed_kernel<<<M_TOK, 128, 0, stream>>>(x, gen, dom, emb);

    // conv1 (+concat conv2) + relu
    transpose_w_kernel<<<(128*400*5 + 255)/256, 256, 0, stream>>>(w1, w1T, 128, 400, 5);
    transpose_w_kernel<<<(128*400*3 + 255)/256, 256, 0, stream>>>(w2, w2T, 128, 400, 3);
    conv1_v2<<<dim3(64, 8), 256, 0, stream>>>(emb, w1T, b1, w2T, b2, bufA);

    // conv3..5
    transpose_w_kernel<<<(256*256*5 + 255)/256, 256, 0, stream>>>(w3, wscr, 256, 256, 5);
    conv256_v2<<<dim3(64, 8), 256, 0, stream>>>(bufA, wscr, b3, bufB);
    transpose_w_kernel<<<(256*256*5 + 255)/256, 256, 0, stream>>>(w4, wscr, 256, 256, 5);
    conv256_v2<<<dim3(64, 8), 256, 0, stream>>>(bufB, wscr, b4, bufA);
    transpose_w_kernel<<<(256*256*5 + 255)/256, 256, 0, stream>>>(w5, wscr, 256, 256, 5);
    conv256_v2<<<dim3(64, 8), 256, 0, stream>>>(bufA, wscr, b5, bufB);
    // xc = bufB

    // attention
    qv_kernel<<<M_TOK, 64, 0, stream>>>(bufB, wq, bq, wv, bv, qb, vb);
    attn_kernel<<<M_TOK, 128, 0, stream>>>(bufB, qb, vb, vv, xmask, xc2);

    // hop 0: f0 = xc2@wc[0:256]+bc, g0 = xc2@wc[256:512]
    proj6_dual_kernel<<<dim3(M_TOK, 2), 64, 0, stream>>>(
        xc2, wc, bc, f0, xc2, wc + 256*6, nullptr, g0, 256);
    lm_scan_v2<<<48, 128, 0, stream>>>(f0, g0, lm0);

    // hop 1
    hop_gemm_v2<<<dim3(64, 8), 256, 0, stream>>>(xc2, 256, 8, wf,           wf, 512, lm0, f0, bf,      F1);
    hop_gemm_v2<<<dim3(64, 8), 256, 0, stream>>>(xc2, 256, 8, wf + 256*512, wf, 518, lm0, g0, nullptr, G1);
    proj6_dual_kernel<<<dim3(M_TOK, 2), 64, 0, stream>>>(
        F1, wc, bc, f1, G1, wc, nullptr, g1, 512);
    lm_scan_v2<<<48, 128, 0, stream>>>(f1, g1, lm1);

    // hop 2
    hop_gemm_v2<<<dim3(64, 8), 256, 0, stream>>>(F1, 512, 9, wf, wf, 512, lm1, f1, bf,      F2);
    hop_gemm_v2<<<dim3(64, 8), 256, 0, stream>>>(G1, 512, 9, wf, wf, 518, lm1, g1, nullptr, G2);
    proj6_dual_kernel<<<dim3(M_TOK, 2), 64, 0, stream>>>(
        F2, wc, bc, f2, G2, wc, nullptr, g2, 512);

    // out[b,i,j,c] = f2[b,i,c] + g2[b,j,c]
    writeout_kernel<<<(BB*LSEQ*LSEQ*6)/256, 256, 0, stream>>>(f2, g2, (float*)d_out);
}

// Round 4
// 310.558 us; speedup vs baseline: 2.3424x; 1.1736x over previous
//
#include <hip/hip_runtime.h>
#include <hip/hip_bf16.h>
#include <math.h>

#define LSEQ 128
#define BB 8
#define M_TOK (BB*LSEQ)   // 1024

// ---------------- all weight transposes in one launch ----------------
struct TransArgs {
    const float* src[5];
    float* dst[5];
    int OC[5], CI[5], K[5];
};
__global__ __launch_bounds__(256) void transpose_all_kernel(TransArgs a) {
    int y = blockIdx.y;
    int idx = blockIdx.x * 256 + threadIdx.x;
    int OC = a.OC[y], CI = a.CI[y], K = a.K[y];
    int total = OC * CI * K;
    if (idx >= total) return;
    int k = idx % K;
    int r = idx / K;
    int ci = r % CI;
    int oc = r / CI;
    a.dst[y][(ci * K + k) * OC + oc] = a.src[y][idx];
}

// ---------------- embedding gather (float4) ----------------
__global__ __launch_bounds__(128) void embed_kernel(const int* __restrict__ x,
        const float4* __restrict__ gen4, const float4* __restrict__ dom4,
        float4* __restrict__ emb4) {
    int m = blockIdx.x;          // b*L + l
    int t = x[m];
    int i = threadIdx.x;
    if (i < 100) {
        float4 v = (i < 75) ? gen4[t * 75 + i] : dom4[t * 25 + (i - 75)];
        emb4[m * 100 + i] = v;
    }
}

// ---------------- conv1: 400ch -> 128(k=5,p=2) ++ 128(k=3,p=1), relu ----------------
__global__ __launch_bounds__(256) void conv1_v2(const float* __restrict__ emb,
        const float* __restrict__ w1T, const float* __restrict__ b1,
        const float* __restrict__ w2T, const float* __restrict__ b2,
        float* __restrict__ out) {
    __shared__ float xs[400 * 20];   // 32 KB
    int pt = blockIdx.x;
    int b = pt >> 3;
    int l0 = (pt & 7) << 4;
    int ot = blockIdx.y;             // 0..3: conv k=5, 4..7: conv k=3
    int tid = threadIdx.x;
    for (int idx = tid; idx < 400 * 20; idx += 256) {
        int p = idx / 400;
        int ci = idx - p * 400;
        int l = l0 - 2 + p;
        float v = 0.f;
        if (l >= 0 && l < LSEQ) v = emb[(b * LSEQ + l) * 400 + ci];
        xs[ci * 20 + p] = v;
    }
    __syncthreads();
    int o = tid & 31;
    int s = tid >> 5;                // ci-slice [s*50, s*50+50)
    float acc[16];
    #pragma unroll
    for (int p = 0; p < 16; ++p) acc[p] = 0.f;
    if (ot < 4) {
        const float* wp = w1T + (s * 50 * 5) * 128 + ot * 32 + o;
        for (int i = 0; i < 50; ++i) {
            const float4* x4 = (const float4*)(xs + (s * 50 + i) * 20);
            float4 A0 = x4[0], A1 = x4[1], A2 = x4[2], A3 = x4[3], A4 = x4[4];
            float xv[20] = {A0.x,A0.y,A0.z,A0.w, A1.x,A1.y,A1.z,A1.w,
                            A2.x,A2.y,A2.z,A2.w, A3.x,A3.y,A3.z,A3.w,
                            A4.x,A4.y,A4.z,A4.w};
            #pragma unroll
            for (int k = 0; k < 5; ++k) {
                float w = wp[k * 128];
                #pragma unroll
                for (int p = 0; p < 16; ++p) acc[p] += w * xv[p + k];
            }
            wp += 640;
        }
    } else {
        const float* wp = w2T + (s * 50 * 3) * 128 + (ot - 4) * 32 + o;
        for (int i = 0; i < 50; ++i) {
            const float4* x4 = (const float4*)(xs + (s * 50 + i) * 20);
            float4 A0 = x4[0], A1 = x4[1], A2 = x4[2], A3 = x4[3], A4 = x4[4];
            float xv[20] = {A0.x,A0.y,A0.z,A0.w, A1.x,A1.y,A1.z,A1.w,
                            A2.x,A2.y,A2.z,A2.w, A3.x,A3.y,A3.z,A3.w,
                            A4.x,A4.y,A4.z,A4.w};
            #pragma unroll
            for (int k = 0; k < 3; ++k) {
                float w = wp[k * 128];
                #pragma unroll
                for (int p = 0; p < 16; ++p) acc[p] += w * xv[p + k + 1];
            }
            wp += 384;
        }
    }
    __syncthreads();
    float* rs = xs;
    #pragma unroll
    for (int p = 0; p < 16; ++p) rs[s * 512 + p * 32 + o] = acc[p];
    __syncthreads();
    #pragma unroll
    for (int r = 0; r < 2; ++r) {
        int idx = r * 256 + tid;
        int p = idx >> 5, oo = idx & 31;
        float sum = 0.f;
        #pragma unroll
        for (int ss = 0; ss < 8; ++ss) sum += rs[ss * 512 + p * 32 + oo];
        float bs = (ot < 4) ? b1[ot * 32 + oo] : b2[(ot - 4) * 32 + oo];
        out[(b * LSEQ + l0 + p) * 256 + ot * 32 + oo] = fmaxf(sum + bs, 0.f);
    }
}

// ---------------- conv256: 256->256, k=5, p=2, relu ----------------
__global__ __launch_bounds__(256) void conv256_v2(const float* __restrict__ in,
        const float* __restrict__ wT, const float* __restrict__ bias,
        float* __restrict__ out) {
    __shared__ float xs[256 * 20];
    int pt = blockIdx.x;
    int b = pt >> 3;
    int l0 = (pt & 7) << 4;
    int ot = blockIdx.y;
    int tid = threadIdx.x;
    for (int idx = tid; idx < 256 * 20; idx += 256) {
        int p = idx >> 8;
        int ci = idx & 255;
        int l = l0 - 2 + p;
        float v = 0.f;
        if (l >= 0 && l < LSEQ) v = in[(b * LSEQ + l) * 256 + ci];
        xs[ci * 20 + p] = v;
    }
    __syncthreads();
    int o = tid & 31;
    int s = tid >> 5;
    int oc0 = ot * 32;
    float acc[16];
    #pragma unroll
    for (int p = 0; p < 16; ++p) acc[p] = 0.f;
    const float* wp = wT + (s * 32 * 5) * 256 + oc0 + o;
    for (int i = 0; i < 32; ++i) {
        const float4* x4 = (const float4*)(xs + (s * 32 + i) * 20);
        float4 A0 = x4[0], A1 = x4[1], A2 = x4[2], A3 = x4[3], A4 = x4[4];
        float xv[20] = {A0.x,A0.y,A0.z,A0.w, A1.x,A1.y,A1.z,A1.w,
                        A2.x,A2.y,A2.z,A2.w, A3.x,A3.y,A3.z,A3.w,
                        A4.x,A4.y,A4.z,A4.w};
        #pragma unroll
        for (int k = 0; k < 5; ++k) {
            float w = wp[k * 256];
            #pragma unroll
            for (int p = 0; p < 16; ++p) acc[p] += w * xv[p + k];
        }
        wp += 1280;
    }
    __syncthreads();
    float* rs = xs;
    #pragma unroll
    for (int p = 0; p < 16; ++p) rs[s * 512 + p * 32 + o] = acc[p];
    __syncthreads();
    #pragma unroll
    for (int r = 0; r < 2; ++r) {
        int idx = r * 256 + tid;
        int p = idx >> 5, oo = idx & 31;
        float sum = 0.f;
        #pragma unroll
        for (int ss = 0; ss < 8; ++ss) sum += rs[ss * 512 + p * 32 + oo];
        out[(b * LSEQ + l0 + p) * 256 + oc0 + oo] = fmaxf(sum + bias[oc0 + oo], 0.f);
    }
}

// ---------------- q/v projection ----------------
__global__ __launch_bounds__(64) void qv_kernel(const float* __restrict__ xc,
        const float* __restrict__ wq, const float* __restrict__ bq,
        const float* __restrict__ wv, const float* __restrict__ bv,
        float* __restrict__ q, float* __restrict__ v) {
    int m = blockIdx.x;
    int d = threadIdx.x;
    if (d >= 50) return;
    float aq = bq[d], av = bv[d];
    for (int c = 0; c < 256; ++c) {
        float xv = xc[m * 256 + c];
        aq += xv * wq[c * 50 + d];
        av += xv * wv[c * 50 + d];
    }
    q[m * 50 + d] = aq;
    v[m * 50 + d] = av;
}

// ---------------- attention + fused f0/g0 projection ----------------
__global__ __launch_bounds__(128) void attn_kernel(const float* __restrict__ xc,
        const float* __restrict__ q, const float* __restrict__ v,
        const float* __restrict__ vv, const float* __restrict__ xmask,
        const float* __restrict__ wc, const float* __restrict__ bc,
        float* __restrict__ xc2, float* __restrict__ f0, float* __restrict__ g0) {
    __shared__ float qrow[50], vvs[50], red[128], aarr[128], xrow[256];
    int bi = blockIdx.x;          // b*L + i
    int b = bi >> 7;
    int tid = threadIdx.x;        // j
    if (tid < 50) { qrow[tid] = q[bi * 50 + tid]; vvs[tid] = vv[tid]; }
    __syncthreads();
    const float* vj = v + (b * LSEQ + tid) * 50;
    float s = 0.f;
    for (int d = 0; d < 50; ++d) s += tanhf(qrow[d] + vj[d]) * vvs[d];
    if (xmask[b * LSEQ + tid] == 0.f) s = -1e9f;
    red[tid] = s; __syncthreads();
    for (int off = 64; off >= 1; off >>= 1) {
        if (tid < off) red[tid] = fmaxf(red[tid], red[tid + off]);
        __syncthreads();
    }
    float mx = red[0];
    __syncthreads();
    float e = expf(s - mx);
    red[tid] = e; __syncthreads();
    for (int off = 64; off >= 1; off >>= 1) {
        if (tid < off) red[tid] += red[tid + off];
        __syncthreads();
    }
    float denom = red[0];
    __syncthreads();
    aarr[tid] = e / denom;
    __syncthreads();
    float maskI = xmask[bi];
    for (int c = tid; c < 256; c += 128) {
        float acc = 0.f;
        for (int j = 0; j < LSEQ; ++j) acc += aarr[j] * xc[(b * LSEQ + j) * 256 + c];
        float val = xc[bi * 256 + c] + acc * maskI;
        xc2[bi * 256 + c] = val;
        xrow[c] = val;
    }
    __syncthreads();
    if (tid < 12) {
        float acc = 0.f;
        if (tid < 6) {
            for (int ch = 0; ch < 256; ++ch) acc += xrow[ch] * wc[ch * 6 + tid];
            f0[bi * 6 + tid] = acc + bc[tid];
        } else {
            int c = tid - 6;
            for (int ch = 0; ch < 256; ++ch) acc += xrow[ch] * wc[(256 + ch) * 6 + c];
            g0[bi * 6 + c] = acc;
        }
    }
}

// ---------------- precompute 1: Wfc[r,c] = sum_n wf[r,n]*wc[n,c], r<512 ----------------
__global__ __launch_bounds__(64) void precomp1_kernel(const float* __restrict__ wf,
        const float* __restrict__ wc, float* __restrict__ Wfc) {
    int r = blockIdx.x;
    int tid = threadIdx.x;
    float p[6] = {0,0,0,0,0,0};
    const float* row = wf + r * 512;
    for (int n = tid; n < 512; n += 64) {
        float a = row[n];
        #pragma unroll
        for (int c = 0; c < 6; ++c) p[c] += a * wc[n * 6 + c];
    }
    #pragma unroll
    for (int c = 0; c < 6; ++c)
        for (int off = 32; off >= 1; off >>= 1) p[c] += __shfl_xor(p[c], off, 64);
    if (tid == 0) {
        #pragma unroll
        for (int c = 0; c < 6; ++c) Wfc[r * 6 + c] = p[c];
    }
}

// ---------------- precompute 2: U[r,c] (531 x 12); P = [wc | Wfc]; row 530 = bf ----------------
__global__ __launch_bounds__(64) void precomp2_kernel(const float* __restrict__ wf,
        const float* __restrict__ bf, const float* __restrict__ wc,
        const float* __restrict__ Wfc, float* __restrict__ U) {
    int r = blockIdx.x;                    // 0..530
    int tid = threadIdx.x;
    const float* row = (r < 530) ? (wf + r * 512) : bf;
    float p[12];
    #pragma unroll
    for (int c = 0; c < 12; ++c) p[c] = 0.f;
    for (int n = tid; n < 512; n += 64) {
        float a = row[n];
        #pragma unroll
        for (int c = 0; c < 6; ++c) {
            p[c]     += a * wc[n * 6 + c];
            p[c + 6] += a * Wfc[n * 6 + c];
        }
    }
    #pragma unroll
    for (int c = 0; c < 12; ++c)
        for (int off = 32; off >= 1; off >>= 1) p[c] += __shfl_xor(p[c], off, 64);
    if (tid == 0) {
        #pragma unroll
        for (int c = 0; c < 12; ++c) U[r * 12 + c] = p[c];
    }
}

// ---------------- lm scan (strided input): parallel prefix/suffix max ----------------
__global__ __launch_bounds__(128) void lm_scan_v3(const float* __restrict__ f,
        const float* __restrict__ g, int stride, float* __restrict__ lm) {
    __shared__ float sf[128], sg[128];
    int bc = blockIdx.x;          // b*6 + c
    int b = bc / 6, c = bc - b * 6;
    int p = threadIdx.x;
    float fv = f[(b * LSEQ + p) * stride + c];
    float gv = g[(b * LSEQ + p) * stride + c];
    sf[p] = fv; sg[p] = gv;
    __syncthreads();
    float pf = fv, sgx = gv;
    #pragma unroll
    for (int off = 1; off < 128; off <<= 1) {
        float a = (p >= off) ? sf[p - off] : -INFINITY;
        float d = (p + off < 128) ? sg[p + off] : -INFINITY;
        __syncthreads();
        pf = fmaxf(pf, a); sgx = fmaxf(sgx, d);
        sf[p] = pf; sg[p] = sgx;
        __syncthreads();
    }
    float M1 = pf + gv;
    if (p < LSEQ - 1) M1 = fmaxf(M1, 0.f);
    float M2 = fv + sgx;
    if (p > 0) M2 = fmaxf(M2, 0.f);
    lm[(b * LSEQ + p) * 6 + c] = fmaxf(M1, M2);
}

// ---------------- hop fold: [f1,phi1] / [g1,gam1] per token ----------------
__global__ __launch_bounds__(64) void hopfold_kernel(const float* __restrict__ xc2,
        const float* __restrict__ U, const float* __restrict__ lm0,
        const float* __restrict__ f0, const float* __restrict__ g0,
        const float* __restrict__ bc,
        float* __restrict__ outF, float* __restrict__ outG) {
    int m = blockIdx.x;
    int y = blockIdx.y;
    int tid = threadIdx.x;
    const float* Urows = U + (y ? 256 : 0) * 12;
    float p[12];
    #pragma unroll
    for (int c = 0; c < 12; ++c) p[c] = 0.f;
    for (int k = tid; k < 256; k += 64) {
        float a = xc2[m * 256 + k];
        const float* ur = Urows + k * 12;
        #pragma unroll
        for (int c = 0; c < 12; ++c) p[c] += a * ur[c];
    }
    #pragma unroll
    for (int c = 0; c < 12; ++c)
        for (int off = 32; off >= 1; off >>= 1) p[c] += __shfl_xor(p[c], off, 64);
    if (tid == 0) {
        const float* Bb = U + (y ? 518 : 512) * 12;
        const float* Db = U + 524 * 12;
        const float* fg = y ? g0 : f0;
        float* out = y ? outG : outF;
        float lmv[6], fgv[6];
        #pragma unroll
        for (int j = 0; j < 6; ++j) { lmv[j] = lm0[m * 6 + j]; fgv[j] = fg[m * 6 + j]; }
        #pragma unroll
        for (int c = 0; c < 12; ++c) {
            float s = p[c];
            #pragma unroll
            for (int j = 0; j < 6; ++j) s += lmv[j] * Bb[j * 12 + c] + fgv[j] * Db[j * 12 + c];
            if (!y) { s += U[530 * 12 + c]; if (c < 6) s += bc[c]; }
            out[m * 12 + c] = s;
        }
    }
}

// ---------------- f2/g2 finalize (FIXED: grid-stride LDS staging) ----------------
__global__ __launch_bounds__(128) void f2g2_kernel(const float* __restrict__ f1phi,
        const float* __restrict__ g1gam, const float* __restrict__ lm1,
        const float* __restrict__ U, const float* __restrict__ bc,
        float* __restrict__ f2, float* __restrict__ g2) {
    __shared__ float Us[19 * 12], bcs[6];
    int tid = threadIdx.x;
    for (int i = tid; i < 19 * 12; i += 128) Us[i] = U[512 * 12 + i];
    if (tid < 6) bcs[tid] = bc[tid];
    __syncthreads();
    int m = blockIdx.x * 128 + tid;
    float lmv[6], f1v[6], g1v[6];
    #pragma unroll
    for (int j = 0; j < 6; ++j) {
        lmv[j] = lm1[m * 6 + j];
        f1v[j] = f1phi[m * 12 + j];
        g1v[j] = g1gam[m * 12 + j];
    }
    #pragma unroll
    for (int c = 0; c < 6; ++c) {
        float sf = f1phi[m * 12 + 6 + c] + Us[18 * 12 + c] + bcs[c];
        float sg = g1gam[m * 12 + 6 + c];
        #pragma unroll
        for (int j = 0; j < 6; ++j) {
            sf += lmv[j] * Us[j * 12 + c]       + f1v[j] * Us[(12 + j) * 12 + c];
            sg += lmv[j] * Us[(6 + j) * 12 + c] + g1v[j] * Us[(12 + j) * 12 + c];
        }
        f2[m * 6 + c] = sf;
        g2[m * 6 + c] = sg;
    }
}

// ---------------- final separable write ----------------
__global__ __launch_bounds__(256) void writeout_kernel(const float* __restrict__ f2,
        const float* __restrict__ g2, float* __restrict__ out) {
    int idx = blockIdx.x * 256 + threadIdx.x;   // < 8*128*128*6
    int c = idx % 6;
    int r = idx / 6;
    int j = r & 127;
    int bi = r >> 7;
    int b = bi >> 7;
    out[idx] = f2[bi * 6 + c] + g2[(b * LSEQ + j) * 6 + c];
}

extern "C" void kernel_launch(void* const* d_in, const int* in_sizes, int n_in,
                              void* d_out, int out_size, void* d_ws, size_t ws_size,
                              hipStream_t stream) {
    const int*   x     = (const int*)d_in[0];
    const float* xmask = (const float*)d_in[2];
    const float* gen   = (const float*)d_in[3];
    const float* dom   = (const float*)d_in[4];
    const float* w1    = (const float*)d_in[5];
    const float* b1    = (const float*)d_in[6];
    const float* w2    = (const float*)d_in[7];
    const float* b2    = (const float*)d_in[8];
    const float* w3    = (const float*)d_in[9];
    const float* b3    = (const float*)d_in[10];
    const float* w4    = (const float*)d_in[11];
    const float* b4    = (const float*)d_in[12];
    const float* w5    = (const float*)d_in[13];
    const float* b5    = (const float*)d_in[14];
    const float* wq    = (const float*)d_in[15];
    const float* bq    = (const float*)d_in[16];
    const float* wv    = (const float*)d_in[17];
    const float* bv    = (const float*)d_in[18];
    const float* vv    = (const float*)d_in[19];
    const float* wf    = (const float*)d_in[20];
    const float* bf    = (const float*)d_in[21];
    const float* wc    = (const float*)d_in[22];
    const float* bc    = (const float*)d_in[23];

    float* ws = (float*)d_ws;
    float* emb   = ws;                  // 409600
    float* bufA  = emb   + 409600;      // 262144
    float* bufB  = bufA  + 262144;      // 262144
    float* xc2   = bufB  + 262144;      // 262144
    float* qb    = xc2   + 262144;      // 51200
    float* vb    = qb    + 51200;       // 51200
    float* w1T   = vb    + 51200;       // 256000
    float* w2T   = w1T   + 256000;      // 153600
    float* w3T   = w2T   + 153600;      // 327680
    float* w4T   = w3T   + 327680;      // 327680
    float* w5T   = w4T   + 327680;      // 327680
    float* Wfc   = w5T   + 327680;      // 3072
    float* U     = Wfc   + 3072;        // 6372
    float* f0    = U     + 6372;        // 6144
    float* g0    = f0    + 6144;
    float* lm0   = g0    + 6144;
    float* lm1   = lm0   + 6144;
    float* f1phi = lm1   + 6144;        // 12288
    float* g1gam = f1phi + 12288;       // 12288
    float* f2    = g1gam + 12288;       // 6144
    float* g2    = f2    + 6144;

    // --- precompute folded hop matrices ---
    precomp1_kernel<<<512, 64, 0, stream>>>(wf, wc, Wfc);
    precomp2_kernel<<<531, 64, 0, stream>>>(wf, bf, wc, Wfc, U);

    // --- embedding ---
    embed_kernel<<<M_TOK, 128, 0, stream>>>(x, (const float4*)gen, (const float4*)dom,
                                            (float4*)emb);

    // --- all weight transposes, one launch ---
    TransArgs ta;
    ta.src[0] = w1;  ta.dst[0] = w1T; ta.OC[0] = 128; ta.CI[0] = 400; ta.K[0] = 5;
    ta.src[1] = w2;  ta.dst[1] = w2T; ta.OC[1] = 128; ta.CI[1] = 400; ta.K[1] = 3;
    ta.src[2] = w3;  ta.dst[2] = w3T; ta.OC[2] = 256; ta.CI[2] = 256; ta.K[2] = 5;
    ta.src[3] = w4;  ta.dst[3] = w4T; ta.OC[3] = 256; ta.CI[3] = 256; ta.K[3] = 5;
    ta.src[4] = w5;  ta.dst[4] = w5T; ta.OC[4] = 256; ta.CI[4] = 256; ta.K[4] = 5;
    transpose_all_kernel<<<dim3(1280, 5), 256, 0, stream>>>(ta);

    // --- convs ---
    conv1_v2<<<dim3(64, 8), 256, 0, stream>>>(emb, w1T, b1, w2T, b2, bufA);
    conv256_v2<<<dim3(64, 8), 256, 0, stream>>>(bufA, w3T, b3, bufB);
    conv256_v2<<<dim3(64, 8), 256, 0, stream>>>(bufB, w4T, b4, bufA);
    conv256_v2<<<dim3(64, 8), 256, 0, stream>>>(bufA, w5T, b5, bufB);
    // xc = bufB

    // --- attention (+ fused f0/g0) ---
    qv_kernel<<<M_TOK, 64, 0, stream>>>(bufB, wq, bq, wv, bv, qb, vb);
    attn_kernel<<<M_TOK, 128, 0, stream>>>(bufB, qb, vb, vv, xmask, wc, bc, xc2, f0, g0);

    // --- hops (fully folded) ---
    lm_scan_v3<<<48, 128, 0, stream>>>(f0, g0, 6, lm0);
    hopfold_kernel<<<dim3(M_TOK, 2), 64, 0, stream>>>(xc2, U, lm0, f0, g0, bc, f1phi, g1gam);
    lm_scan_v3<<<48, 128, 0, stream>>>(f1phi, g1gam, 12, lm1);
    f2g2_kernel<<<8, 128, 0, stream>>>(f1phi, g1gam, lm1, U, bc, f2, g2);

    // --- out[b,i,j,c] = f2[b,i,c] + g2[b,j,c] ---
    writeout_kernel<<<(BB*LSEQ*LSEQ*6)/256, 256, 0, stream>>>(f2, g2, (float*)d_out);
}

// Round 5
// 270.282 us; speedup vs baseline: 2.6914x; 1.1490x over previous
//
#include <hip/hip_runtime.h>
#include <hip/hip_bf16.h>
#include <math.h>

#define LSEQ 128
#define BB 8
#define M_TOK (BB*LSEQ)   // 1024

// ---------------- staging: 5 weight transposes + embedding gather, one launch ----------------
struct PreArgs {
    const float* src[5];
    float* dst[5];
    int OC[5], CI[5], K[5];
    const int* x;
    const float4* gen4;
    const float4* dom4;
    float4* emb4;
};
__global__ __launch_bounds__(256) void stage_kernel(PreArgs a) {
    int y = blockIdx.y;
    if (y < 5) {
        int idx = blockIdx.x * 256 + threadIdx.x;
        int OC = a.OC[y], CI = a.CI[y], K = a.K[y];
        int total = OC * CI * K;
        if (idx >= total) return;
        int k = idx % K;
        int r = idx / K;
        int ci = r % CI;
        int oc = r / CI;
        a.dst[y][(ci * K + k) * OC + oc] = a.src[y][idx];
    } else {
        int m = blockIdx.x;
        if (m >= M_TOK) return;
        int t = a.x[m];
        int i = threadIdx.x;
        if (i < 100) {
            float4 v = (i < 75) ? a.gen4[t * 75 + i] : a.dom4[t * 25 + (i - 75)];
            a.emb4[m * 100 + i] = v;
        }
    }
}

// ---------------- conv1: 400ch -> 128(k=5,p=2) ++ 128(k=3,p=1), relu ----------------
__global__ __launch_bounds__(256) void conv1_v2(const float* __restrict__ emb,
        const float* __restrict__ w1T, const float* __restrict__ b1,
        const float* __restrict__ w2T, const float* __restrict__ b2,
        float* __restrict__ out) {
    __shared__ float xs[400 * 20];   // 32 KB
    int pt = blockIdx.x;
    int b = pt >> 3;
    int l0 = (pt & 7) << 4;
    int ot = blockIdx.y;             // 0..3: conv k=5, 4..7: conv k=3
    int tid = threadIdx.x;
    for (int idx = tid; idx < 400 * 20; idx += 256) {
        int p = idx / 400;
        int ci = idx - p * 400;
        int l = l0 - 2 + p;
        float v = 0.f;
        if (l >= 0 && l < LSEQ) v = emb[(b * LSEQ + l) * 400 + ci];
        xs[ci * 20 + p] = v;
    }
    __syncthreads();
    int o = tid & 31;
    int s = tid >> 5;                // ci-slice [s*50, s*50+50)
    float acc[16];
    #pragma unroll
    for (int p = 0; p < 16; ++p) acc[p] = 0.f;
    if (ot < 4) {
        const float* wp = w1T + (s * 50 * 5) * 128 + ot * 32 + o;
        for (int i = 0; i < 50; ++i) {
            const float4* x4 = (const float4*)(xs + (s * 50 + i) * 20);
            float4 A0 = x4[0], A1 = x4[1], A2 = x4[2], A3 = x4[3], A4 = x4[4];
            float xv[20] = {A0.x,A0.y,A0.z,A0.w, A1.x,A1.y,A1.z,A1.w,
                            A2.x,A2.y,A2.z,A2.w, A3.x,A3.y,A3.z,A3.w,
                            A4.x,A4.y,A4.z,A4.w};
            #pragma unroll
            for (int k = 0; k < 5; ++k) {
                float w = wp[k * 128];
                #pragma unroll
                for (int p = 0; p < 16; ++p) acc[p] += w * xv[p + k];
            }
            wp += 640;
        }
    } else {
        const float* wp = w2T + (s * 50 * 3) * 128 + (ot - 4) * 32 + o;
        for (int i = 0; i < 50; ++i) {
            const float4* x4 = (const float4*)(xs + (s * 50 + i) * 20);
            float4 A0 = x4[0], A1 = x4[1], A2 = x4[2], A3 = x4[3], A4 = x4[4];
            float xv[20] = {A0.x,A0.y,A0.z,A0.w, A1.x,A1.y,A1.z,A1.w,
                            A2.x,A2.y,A2.z,A2.w, A3.x,A3.y,A3.z,A3.w,
                            A4.x,A4.y,A4.z,A4.w};
            #pragma unroll
            for (int k = 0; k < 3; ++k) {
                float w = wp[k * 128];
                #pragma unroll
                for (int p = 0; p < 16; ++p) acc[p] += w * xv[p + k + 1];
            }
            wp += 384;
        }
    }
    __syncthreads();
    float* rs = xs;
    #pragma unroll
    for (int p = 0; p < 16; ++p) rs[s * 512 + p * 32 + o] = acc[p];
    __syncthreads();
    #pragma unroll
    for (int r = 0; r < 2; ++r) {
        int idx = r * 256 + tid;
        int p = idx >> 5, oo = idx & 31;
        float sum = 0.f;
        #pragma unroll
        for (int ss = 0; ss < 8; ++ss) sum += rs[ss * 512 + p * 32 + oo];
        float bs = (ot < 4) ? b1[ot * 32 + oo] : b2[(ot - 4) * 32 + oo];
        out[(b * LSEQ + l0 + p) * 256 + ot * 32 + oo] = fmaxf(sum + bs, 0.f);
    }
}

// ---------------- conv256: 256->256, k=5, p=2, relu ----------------
__global__ __launch_bounds__(256) void conv256_v2(const float* __restrict__ in,
        const float* __restrict__ wT, const float* __restrict__ bias,
        float* __restrict__ out) {
    __shared__ float xs[256 * 20];
    int pt = blockIdx.x;
    int b = pt >> 3;
    int l0 = (pt & 7) << 4;
    int ot = blockIdx.y;
    int tid = threadIdx.x;
    for (int idx = tid; idx < 256 * 20; idx += 256) {
        int p = idx >> 8;
        int ci = idx & 255;
        int l = l0 - 2 + p;
        float v = 0.f;
        if (l >= 0 && l < LSEQ) v = in[(b * LSEQ + l) * 256 + ci];
        xs[ci * 20 + p] = v;
    }
    __syncthreads();
    int o = tid & 31;
    int s = tid >> 5;
    int oc0 = ot * 32;
    float acc[16];
    #pragma unroll
    for (int p = 0; p < 16; ++p) acc[p] = 0.f;
    const float* wp = wT + (s * 32 * 5) * 256 + oc0 + o;
    for (int i = 0; i < 32; ++i) {
        const float4* x4 = (const float4*)(xs + (s * 32 + i) * 20);
        float4 A0 = x4[0], A1 = x4[1], A2 = x4[2], A3 = x4[3], A4 = x4[4];
        float xv[20] = {A0.x,A0.y,A0.z,A0.w, A1.x,A1.y,A1.z,A1.w,
                        A2.x,A2.y,A2.z,A2.w, A3.x,A3.y,A3.z,A3.w,
                        A4.x,A4.y,A4.z,A4.w};
        #pragma unroll
        for (int k = 0; k < 5; ++k) {
            float w = wp[k * 256];
            #pragma unroll
            for (int p = 0; p < 16; ++p) acc[p] += w * xv[p + k];
        }
        wp += 1280;
    }
    __syncthreads();
    float* rs = xs;
    #pragma unroll
    for (int p = 0; p < 16; ++p) rs[s * 512 + p * 32 + o] = acc[p];
    __syncthreads();
    #pragma unroll
    for (int r = 0; r < 2; ++r) {
        int idx = r * 256 + tid;
        int p = idx >> 5, oo = idx & 31;
        float sum = 0.f;
        #pragma unroll
        for (int ss = 0; ss < 8; ++ss) sum += rs[ss * 512 + p * 32 + oo];
        out[(b * LSEQ + l0 + p) * 256 + oc0 + oo] = fmaxf(sum + bias[oc0 + oo], 0.f);
    }
}

// ---------------- q/v projection: 2 waves per block (wave0=q, wave1=v) ----------------
__global__ __launch_bounds__(128) void qv_v2(const float* __restrict__ xc,
        const float* __restrict__ wq, const float* __restrict__ bq,
        const float* __restrict__ wv, const float* __restrict__ bv,
        float* __restrict__ q, float* __restrict__ v) {
    int m = blockIdx.x;
    int tid = threadIdx.x;
    int w = tid >> 6, d = tid & 63;
    if (d >= 50) return;
    const float* W = w ? wv : wq;
    float a = w ? bv[d] : bq[d];
    const float* xm = xc + m * 256;
    #pragma unroll 8
    for (int c = 0; c < 256; ++c) a += xm[c] * W[c * 50 + d];
    (w ? v : q)[m * 50 + d] = a;
}

// ---------------- attention v2: 256 threads/row, LDS-staged V, fast tanh ----------------
// scores_j = sum_d tanh(q_i[d]+v_j[d])*vv[d]; softmax_j; merged = attn@xc;
// xc2 = xc + merged*mask_i; f0/g0 = xc2@wc halves
__global__ __launch_bounds__(256) void attn_v2(const float* __restrict__ xc,
        const float* __restrict__ q, const float* __restrict__ v,
        const float* __restrict__ vv, const float* __restrict__ xmask,
        const float* __restrict__ wc, const float* __restrict__ bc,
        float* __restrict__ xc2, float* __restrict__ f0, float* __restrict__ g0) {
    __shared__ float vs[128 * 50];   // 25.6 KB: v rows of this batch
    __shared__ float spart[128], aarr[128], xrow[256], qrow[52], vvs[52], red[4];
    int bi = blockIdx.x;             // b*L + i
    int b = bi >> 7;
    int tid = threadIdx.x;
    // stage v_b coalesced + q row + vv
    for (int idx = tid; idx < 128 * 50; idx += 256) vs[idx] = v[b * 6400 + idx];
    if (tid < 50) { qrow[tid] = q[bi * 50 + tid]; vvs[tid] = vv[tid]; }
    __syncthreads();
    // scores: 2 threads per j, each 25 d's
    int j = tid & 127, half = tid >> 7;
    int d0 = half * 25;
    const float* vj = vs + j * 50 + d0;
    float s = 0.f;
    #pragma unroll
    for (int d = 0; d < 25; ++d) {
        float x = qrow[d0 + d] + vj[d];
        float e = __expf(2.f * x);               // tanh(x) = 1 - 2/(e^(2x)+1)
        s += (1.f - 2.f / (e + 1.f)) * vvs[d0 + d];
    }
    if (half) spart[j] = s;
    __syncthreads();
    float stot = 0.f;
    if (!half) {
        stot = s + spart[j];
        if (xmask[b * LSEQ + j] == 0.f) stot = -1e9f;
    }
    // softmax over 128 (waves 0,1 hold the values)
    if (tid < 128) {
        float m = stot;
        #pragma unroll
        for (int off = 32; off >= 1; off >>= 1) m = fmaxf(m, __shfl_xor(m, off, 64));
        if ((tid & 63) == 0) red[tid >> 6] = m;
    }
    __syncthreads();
    float mx = fmaxf(red[0], red[1]);
    float e = 0.f;
    if (tid < 128) {
        e = __expf(stot - mx);
        float su = e;
        #pragma unroll
        for (int off = 32; off >= 1; off >>= 1) su += __shfl_xor(su, off, 64);
        if ((tid & 63) == 0) red[2 + (tid >> 6)] = su;
    }
    __syncthreads();
    float denom = red[2] + red[3];
    if (tid < 128) aarr[j] = e / denom;
    __syncthreads();
    // merged: c = tid (256 channels), coalesced xc reads, aarr broadcast
    float maskI = xmask[bi];
    const float* xcb = xc + b * LSEQ * 256;
    float acc = 0.f;
    #pragma unroll 8
    for (int jj = 0; jj < 128; ++jj) acc += aarr[jj] * xcb[jj * 256 + tid];
    float val = xc[bi * 256 + tid] + acc * maskI;
    xc2[bi * 256 + tid] = val;
    xrow[tid] = val;
    __syncthreads();
    // f0/g0: 12 outputs x 16 lanes
    int grp = tid >> 4, l16 = tid & 15;
    if (grp < 12) {
        int c = grp % 6, gsel = grp / 6;
        const float* wcc = wc + gsel * 256 * 6 + c;
        float a = 0.f;
        #pragma unroll
        for (int ch = l16; ch < 256; ch += 16) a += xrow[ch] * wcc[ch * 6];
        #pragma unroll
        for (int off = 8; off >= 1; off >>= 1) a += __shfl_down(a, off, 16);
        if (l16 == 0) {
            if (gsel == 0) f0[bi * 6 + c] = a + bc[c];
            else           g0[bi * 6 + c] = a;
        }
    }
}

// ---------------- precompute 1: Wfc[r,c] = sum_n wf[r,n]*wc[n,c], r<512 ----------------
__global__ __launch_bounds__(64) void precomp1_kernel(const float* __restrict__ wf,
        const float* __restrict__ wc, float* __restrict__ Wfc) {
    int r = blockIdx.x;
    int tid = threadIdx.x;
    float p[6] = {0,0,0,0,0,0};
    const float* row = wf + r * 512;
    for (int n = tid; n < 512; n += 64) {
        float a = row[n];
        #pragma unroll
        for (int c = 0; c < 6; ++c) p[c] += a * wc[n * 6 + c];
    }
    #pragma unroll
    for (int c = 0; c < 6; ++c)
        for (int off = 32; off >= 1; off >>= 1) p[c] += __shfl_xor(p[c], off, 64);
    if (tid == 0) {
        #pragma unroll
        for (int c = 0; c < 6; ++c) Wfc[r * 6 + c] = p[c];
    }
}

// ---------------- precompute 2: U (531 x 12) = wf_rows @ [wc | Wfc]; row 530 = bf ----------------
__global__ __launch_bounds__(64) void precomp2_kernel(const float* __restrict__ wf,
        const float* __restrict__ bf, const float* __restrict__ wc,
        const float* __restrict__ Wfc, float* __restrict__ U) {
    int r = blockIdx.x;                    // 0..530
    int tid = threadIdx.x;
    const float* row = (r < 530) ? (wf + r * 512) : bf;
    float p[12];
    #pragma unroll
    for (int c = 0; c < 12; ++c) p[c] = 0.f;
    for (int n = tid; n < 512; n += 64) {
        float a = row[n];
        #pragma unroll
        for (int c = 0; c < 6; ++c) {
            p[c]     += a * wc[n * 6 + c];
            p[c + 6] += a * Wfc[n * 6 + c];
        }
    }
    #pragma unroll
    for (int c = 0; c < 12; ++c)
        for (int off = 32; off >= 1; off >>= 1) p[c] += __shfl_xor(p[c], off, 64);
    if (tid == 0) {
        #pragma unroll
        for (int c = 0; c < 12; ++c) U[r * 12 + c] = p[c];
    }
}

// ---------------- lm scan (strided input): parallel prefix/suffix max ----------------
__global__ __launch_bounds__(128) void lm_scan_v3(const float* __restrict__ f,
        const float* __restrict__ g, int stride, float* __restrict__ lm) {
    __shared__ float sf[128], sg[128];
    int bc = blockIdx.x;          // b*6 + c
    int b = bc / 6, c = bc - b * 6;
    int p = threadIdx.x;
    float fv = f[(b * LSEQ + p) * stride + c];
    float gv = g[(b * LSEQ + p) * stride + c];
    sf[p] = fv; sg[p] = gv;
    __syncthreads();
    float pf = fv, sgx = gv;
    #pragma unroll
    for (int off = 1; off < 128; off <<= 1) {
        float a = (p >= off) ? sf[p - off] : -INFINITY;
        float d = (p + off < 128) ? sg[p + off] : -INFINITY;
        __syncthreads();
        pf = fmaxf(pf, a); sgx = fmaxf(sgx, d);
        sf[p] = pf; sg[p] = sgx;
        __syncthreads();
    }
    float M1 = pf + gv;
    if (p < LSEQ - 1) M1 = fmaxf(M1, 0.f);
    float M2 = fv + sgx;
    if (p > 0) M2 = fmaxf(M2, 0.f);
    lm[(b * LSEQ + p) * 6 + c] = fmaxf(M1, M2);
}

// ---------------- hop fold: [f1,phi1] / [g1,gam1] per token ----------------
__global__ __launch_bounds__(64) void hopfold_kernel(const float* __restrict__ xc2,
        const float* __restrict__ U, const float* __restrict__ lm0,
        const float* __restrict__ f0, const float* __restrict__ g0,
        const float* __restrict__ bc,
        float* __restrict__ outF, float* __restrict__ outG) {
    int m = blockIdx.x;
    int y = blockIdx.y;
    int tid = threadIdx.x;
    const float* Urows = U + (y ? 256 : 0) * 12;
    float p[12];
    #pragma unroll
    for (int c = 0; c < 12; ++c) p[c] = 0.f;
    for (int k = tid; k < 256; k += 64) {
        float a = xc2[m * 256 + k];
        const float* ur = Urows + k * 12;
        #pragma unroll
        for (int c = 0; c < 12; ++c) p[c] += a * ur[c];
    }
    #pragma unroll
    for (int c = 0; c < 12; ++c)
        for (int off = 32; off >= 1; off >>= 1) p[c] += __shfl_xor(p[c], off, 64);
    if (tid == 0) {
        const float* Bb = U + (y ? 518 : 512) * 12;
        const float* Db = U + 524 * 12;
        const float* fg = y ? g0 : f0;
        float* out = y ? outG : outF;
        float lmv[6], fgv[6];
        #pragma unroll
        for (int j = 0; j < 6; ++j) { lmv[j] = lm0[m * 6 + j]; fgv[j] = fg[m * 6 + j]; }
        #pragma unroll
        for (int c = 0; c < 12; ++c) {
            float s = p[c];
            #pragma unroll
            for (int j = 0; j < 6; ++j) s += lmv[j] * Bb[j * 12 + c] + fgv[j] * Db[j * 12 + c];
            if (!y) { s += U[530 * 12 + c]; if (c < 6) s += bc[c]; }
            out[m * 12 + c] = s;
        }
    }
}

// ---------------- f2/g2 finalize ----------------
__global__ __launch_bounds__(128) void f2g2_kernel(const float* __restrict__ f1phi,
        const float* __restrict__ g1gam, const float* __restrict__ lm1,
        const float* __restrict__ U, const float* __restrict__ bc,
        float* __restrict__ f2, float* __restrict__ g2) {
    __shared__ float Us[19 * 12], bcs[6];
    int tid = threadIdx.x;
    for (int i = tid; i < 19 * 12; i += 128) Us[i] = U[512 * 12 + i];
    if (tid < 6) bcs[tid] = bc[tid];
    __syncthreads();
    int m = blockIdx.x * 128 + tid;
    float lmv[6], f1v[6], g1v[6];
    #pragma unroll
    for (int j = 0; j < 6; ++j) {
        lmv[j] = lm1[m * 6 + j];
        f1v[j] = f1phi[m * 12 + j];
        g1v[j] = g1gam[m * 12 + j];
    }
    #pragma unroll
    for (int c = 0; c < 6; ++c) {
        float sf = f1phi[m * 12 + 6 + c] + Us[18 * 12 + c] + bcs[c];
        float sg = g1gam[m * 12 + 6 + c];
        #pragma unroll
        for (int j = 0; j < 6; ++j) {
            sf += lmv[j] * Us[j * 12 + c]       + f1v[j] * Us[(12 + j) * 12 + c];
            sg += lmv[j] * Us[(6 + j) * 12 + c] + g1v[j] * Us[(12 + j) * 12 + c];
        }
        f2[m * 6 + c] = sf;
        g2[m * 6 + c] = sg;
    }
}

// ---------------- final separable write ----------------
__global__ __launch_bounds__(256) void writeout_kernel(const float* __restrict__ f2,
        const float* __restrict__ g2, float* __restrict__ out) {
    int idx = blockIdx.x * 256 + threadIdx.x;   // < 8*128*128*6
    int c = idx % 6;
    int r = idx / 6;
    int j = r & 127;
    int bi = r >> 7;
    int b = bi >> 7;
    out[idx] = f2[bi * 6 + c] + g2[(b * LSEQ + j) * 6 + c];
}

extern "C" void kernel_launch(void* const* d_in, const int* in_sizes, int n_in,
                              void* d_out, int out_size, void* d_ws, size_t ws_size,
                              hipStream_t stream) {
    const int*   x     = (const int*)d_in[0];
    const float* xmask = (const float*)d_in[2];
    const float* gen   = (const float*)d_in[3];
    const float* dom   = (const float*)d_in[4];
    const float* w1    = (const float*)d_in[5];
    const float* b1    = (const float*)d_in[6];
    const float* w2    = (const float*)d_in[7];
    const float* b2    = (const float*)d_in[8];
    const float* w3    = (const float*)d_in[9];
    const float* b3    = (const float*)d_in[10];
    const float* w4    = (const float*)d_in[11];
    const float* b4    = (const float*)d_in[12];
    const float* w5    = (const float*)d_in[13];
    const float* b5    = (const float*)d_in[14];
    const float* wq    = (const float*)d_in[15];
    const float* bq    = (const float*)d_in[16];
    const float* wv    = (const float*)d_in[17];
    const float* bv    = (const float*)d_in[18];
    const float* vv    = (const float*)d_in[19];
    const float* wf    = (const float*)d_in[20];
    const float* bf    = (const float*)d_in[21];
    const float* wc    = (const float*)d_in[22];
    const float* bc    = (const float*)d_in[23];

    float* ws = (float*)d_ws;
    float* emb   = ws;                  // 409600
    float* bufA  = emb   + 409600;      // 262144
    float* bufB  = bufA  + 262144;      // 262144
    float* xc2   = bufB  + 262144;      // 262144
    float* qb    = xc2   + 262144;      // 51200
    float* vb    = qb    + 51200;       // 51200
    float* w1T   = vb    + 51200;       // 256000
    float* w2T   = w1T   + 256000;      // 153600
    float* w3T   = w2T   + 153600;      // 327680
    float* w4T   = w3T   + 327680;      // 327680
    float* w5T   = w4T   + 327680;      // 327680
    float* Wfc   = w5T   + 327680;      // 3072
    float* U     = Wfc   + 3072;        // 6372
    float* f0    = U     + 6372;        // 6144
    float* g0    = f0    + 6144;
    float* lm0   = g0    + 6144;
    float* lm1   = lm0   + 6144;
    float* f1phi = lm1   + 6144;        // 12288
    float* g1gam = f1phi + 12288;       // 12288
    float* f2    = g1gam + 12288;       // 6144
    float* g2    = f2    + 6144;

    // --- precompute folded hop matrices ---
    precomp1_kernel<<<512, 64, 0, stream>>>(wf, wc, Wfc);
    precomp2_kernel<<<531, 64, 0, stream>>>(wf, bf, wc, Wfc, U);

    // --- staging: all transposes + embedding in one launch ---
    PreArgs pa;
    pa.src[0] = w1;  pa.dst[0] = w1T; pa.OC[0] = 128; pa.CI[0] = 400; pa.K[0] = 5;
    pa.src[1] = w2;  pa.dst[1] = w2T; pa.OC[1] = 128; pa.CI[1] = 400; pa.K[1] = 3;
    pa.src[2] = w3;  pa.dst[2] = w3T; pa.OC[2] = 256; pa.CI[2] = 256; pa.K[2] = 5;
    pa.src[3] = w4;  pa.dst[3] = w4T; pa.OC[3] = 256; pa.CI[3] = 256; pa.K[3] = 5;
    pa.src[4] = w5;  pa.dst[4] = w5T; pa.OC[4] = 256; pa.CI[4] = 256; pa.K[4] = 5;
    pa.x = x; pa.gen4 = (const float4*)gen; pa.dom4 = (const float4*)dom;
    pa.emb4 = (float4*)emb;
    stage_kernel<<<dim3(1280, 6), 256, 0, stream>>>(pa);

    // --- convs ---
    conv1_v2<<<dim3(64, 8), 256, 0, stream>>>(emb, w1T, b1, w2T, b2, bufA);
    conv256_v2<<<dim3(64, 8), 256, 0, stream>>>(bufA, w3T, b3, bufB);
    conv256_v2<<<dim3(64, 8), 256, 0, stream>>>(bufB, w4T, b4, bufA);
    conv256_v2<<<dim3(64, 8), 256, 0, stream>>>(bufA, w5T, b5, bufB);
    // xc = bufB

    // --- attention (+ fused f0/g0) ---
    qv_v2<<<M_TOK, 128, 0, stream>>>(bufB, wq, bq, wv, bv, qb, vb);
    attn_v2<<<M_TOK, 256, 0, stream>>>(bufB, qb, vb, vv, xmask, wc, bc, xc2, f0, g0);

    // --- hops (fully folded) ---
    lm_scan_v3<<<48, 128, 0, stream>>>(f0, g0, 6, lm0);
    hopfold_kernel<<<dim3(M_TOK, 2), 64, 0, stream>>>(xc2, U, lm0, f0, g0, bc, f1phi, g1gam);
    lm_scan_v3<<<48, 128, 0, stream>>>(f1phi, g1gam, 12, lm1);
    f2g2_kernel<<<8, 128, 0, stream>>>(f1phi, g1gam, lm1, U, bc, f2, g2);

    // --- out[b,i,j,c] = f2[b,i,c] + g2[b,j,c] ---
    writeout_kernel<<<(BB*LSEQ*LSEQ*6)/256, 256, 0, stream>>>(f2, g2, (float*)d_out);
}